// Round 11
// baseline (763.284 us; speedup 1.0000x reference)
//
#include <hip/hip_runtime.h>

typedef unsigned short ushort_t;

constexpr int NN = 100000;   // nodes
constexpr int EE = 1600000;  // edges
constexpr int PP = 100000;   // pos/neg samples
constexpr int DH = 128;
constexpr int DM = 512;

using frag_b16 = __attribute__((ext_vector_type(8))) short;   // 8 bf16 (4 VGPRs)
using frag_f32 = __attribute__((ext_vector_type(4))) float;   // 4 fp32 acc

union FragU {
  ushort_t s[8];
  uint4 u;
  frag_b16 f;
};

// split fp32 into bf16 hi (truncate) + bf16 lo (RNE of residual): x ~= hi+lo, err ~2^-17|x|
__device__ inline void split_bf16(float x, ushort_t& hi, ushort_t& lo) {
  unsigned int bx = __float_as_uint(x);
  hi = (ushort_t)(bx >> 16);
  float hf = __uint_as_float(bx & 0xFFFF0000u);
  float r = x - hf;
  unsigned int br = __float_as_uint(r);
  unsigned int rb = br + 0x7FFFu + ((br >> 16) & 1u);  // RNE
  lo = (ushort_t)(rb >> 16);
}

__device__ inline ushort_t rne_bf16(float x) {
  unsigned int u = __float_as_uint(x);
  unsigned int r = u + 0x7FFFu + ((u >> 16) & 1u);
  return (ushort_t)(r >> 16);
}

// unpack 2 bf16 from packed uint: low half -> a (even col), high half -> b (odd col)
__device__ inline void bf2x(unsigned int u, float& a, float& b) {
  a = __uint_as_float(u << 16);
  b = __uint_as_float(u & 0xFFFF0000u);
}

// async global->LDS 16B copy (dest: wave-uniform base + lane*16, src per-lane)
__device__ inline void g2l16(const ushort_t* __restrict__ g, ushort_t* l) {
  __builtin_amdgcn_global_load_lds(
      (const __attribute__((address_space(1))) void*)g,
      (__attribute__((address_space(3))) void*)l, 16, 0, 0);
}

// ---------------- CSR build (sort edges by dst, once per launch) ----------------

__global__ void hist_kernel(const int* __restrict__ dst, int* __restrict__ deg) {
  int i = blockIdx.x * 256 + threadIdx.x;
  if (i < EE) atomicAdd(&deg[dst[i]], 1);
}

__global__ void scan1_kernel(const int* __restrict__ deg, int* __restrict__ inc,
                             int* __restrict__ bsum) {
  __shared__ int buf[2][512];
  int base = blockIdx.x * 512;
  for (int i = threadIdx.x; i < 512; i += 256) {
    int g = base + i;
    buf[0][i] = (g < NN) ? deg[g] : 0;
  }
  __syncthreads();
  int cur = 0;
  for (int off = 1; off < 512; off <<= 1) {
    int nxt = cur ^ 1;
    for (int i = threadIdx.x; i < 512; i += 256) {
      int v = buf[cur][i];
      if (i >= off) v += buf[cur][i - off];
      buf[nxt][i] = v;
    }
    __syncthreads();
    cur = nxt;
  }
  for (int i = threadIdx.x; i < 512; i += 256) {
    int g = base + i;
    if (g < NN) inc[g] = buf[cur][i];
  }
  if (threadIdx.x == 0) bsum[blockIdx.x] = buf[cur][511];
}

__global__ void scan2_kernel(int* __restrict__ bsum, int nb) {
  __shared__ int buf[2][256];
  int i = threadIdx.x;
  buf[0][i] = (i < nb) ? bsum[i] : 0;
  __syncthreads();
  int cur = 0;
  for (int off = 1; off < 256; off <<= 1) {
    int nxt = cur ^ 1;
    int v = buf[cur][i];
    if (i >= off) v += buf[cur][i - off];
    buf[nxt][i] = v;
    __syncthreads();
    cur = nxt;
  }
  if (i < nb) bsum[i] = (i == 0) ? 0 : buf[cur][i - 1];
}

__global__ void scan3_kernel(const int* __restrict__ inc, const int* __restrict__ deg,
                             const int* __restrict__ bsum,
                             int* __restrict__ row_off, int* __restrict__ cursor) {
  int i = blockIdx.x * 256 + threadIdx.x;
  if (i < NN) {
    int excl = inc[i] - deg[i] + bsum[i >> 9];
    row_off[i] = excl;
    cursor[i] = excl;
    if (i == NN - 1) row_off[NN] = excl + deg[i];
  }
}

// Windowed, XCD-affine scatter (round 0 win). Window w handled only by blocks
// with blockIdx&7==w; each csr window written by one XCD -> clean writeback.
constexpr int SC_NW = 8;
constexpr int SC_WND = (NN + SC_NW - 1) / SC_NW;
constexpr int SC_EPB = 8192;
constexpr int SC_CHUNKS = (EE + SC_EPB - 1) / SC_EPB;

__global__ __launch_bounds__(256) void scatter_kernel(const int* __restrict__ esrc,
                                                      const int* __restrict__ edst,
                                                      int* __restrict__ cursor,
                                                      int* __restrict__ csr) {
  const int w = blockIdx.x & (SC_NW - 1);
  const int chunk = blockIdx.x / SC_NW;
  const int lo = w * SC_WND;
  const int hi = lo + SC_WND;
  const int base = chunk * SC_EPB;
  #pragma unroll 4
  for (int it = 0; it < SC_EPB / 256; ++it) {
    int i = base + it * 256 + threadIdx.x;
    if (i < EE) {
      int d = edst[i];
      if (d >= lo && d < hi) {
        int p = atomicAdd(&cursor[d], 1);
        csr[p] = esrc[i];
      }
    }
  }
}

// ---------------- weight packing: MFMA B-frag order, 16B records, RNE bf16 ----------
// record r = tile_global*64+lane holds 8 bf16 at wp + r*8 (ushorts).
// W1 [L][128(K)][512(N)]: tile = tn*4+tk (tn<32,tk<4), n=tn*16+(lane&15), k=tk*32+(lane>>4)*8+j
// -> per 32-col chunk ch, A-panel = tiles [ch*8, ch*8+8) CONTIGUOUS (8KB) for DMA.
__global__ void pack_w1_kernel(const float* __restrict__ W1, ushort_t* __restrict__ wp) {
  int t = blockIdx.x * 256 + threadIdx.x;
  if (t >= 3 * 128 * 64) return;
  int lane = t & 63;
  int tile = t >> 6;
  int tk = tile & 3;
  int tn = (tile >> 2) & 31;
  int layer = tile >> 7;
  int n = tn * 16 + (lane & 15);
  int k0 = tk * 32 + (lane >> 4) * 8;
  const float* src = W1 + (size_t)layer * DH * DM;
  size_t dst = (size_t)t * 8;
  #pragma unroll
  for (int j = 0; j < 8; ++j) wp[dst + j] = rne_bf16(src[(size_t)(k0 + j) * DM + n]);
}

// W2 [L][512(K)][128(N)]: ktg-major tile order: tile = ktg*8+tn (ktg<16, tn<8)
// -> per 32-k slab ch, B-panel = tiles [ch*8, ch*8+8) CONTIGUOUS (8KB) for DMA.
__global__ void pack_w2_kernel(const float* __restrict__ W2, ushort_t* __restrict__ wp) {
  int t = blockIdx.x * 256 + threadIdx.x;
  if (t >= 3 * 128 * 64) return;
  int lane = t & 63;
  int tile = t >> 6;
  int tn = tile & 7;
  int ktg = (tile >> 3) & 15;
  int layer = tile >> 7;
  int n = tn * 16 + (lane & 15);
  int k0 = ktg * 32 + (lane >> 4) * 8;
  const float* src = W2 + (size_t)layer * DM * DH;
  size_t dst = (size_t)t * 8;
  #pragma unroll
  for (int j = 0; j < 8; ++j) wp[dst + j] = rne_bf16(src[(size_t)(k0 + j) * DH + n]);
}

// Wp1 [128(K)][64(N)] -> MFMA B-frag records, tile = tk*4+tn (tk<4,tn<4)
__global__ void pack_wp1_kernel(const float* __restrict__ Wp1, ushort_t* __restrict__ wp) {
  int t = blockIdx.x * 256 + threadIdx.x;
  if (t >= 16 * 64) return;
  int lane = t & 63;
  int tile = t >> 6;
  int tn = tile & 3;
  int tk = tile >> 2;
  int n = tn * 16 + (lane & 15);
  int k0 = tk * 32 + (lane >> 4) * 8;
  size_t dst = (size_t)t * 8;
  #pragma unroll
  for (int j = 0; j < 8; ++j) wp[dst + j] = rne_bf16(Wp1[(size_t)(k0 + j) * 64 + n]);
}

// ---------------- x -> bf16 convert (layer-0 gather source) ----------------
__global__ void cvt_bf16_kernel(const float* __restrict__ x, ushort_t* __restrict__ xb) {
  int i = blockIdx.x * 256 + threadIdx.x;  // n = NN*DH/4 quads
  if (i < NN * DH / 4) {
    float4 v = ((const float4*)x)[i];
    ushort4 o;
    o.x = rne_bf16(v.x); o.y = rne_bf16(v.y); o.z = rne_bf16(v.z); o.w = rne_bf16(v.w);
    ((ushort4*)xb)[i] = o;
  }
}

// ---------------- FUSED agg + MFMA MLP (ROUND 11) ----------
// Round-10 post-mortem: mlp pinned at ~88us across 4 schedule/occupancy levers;
// agg (3 dispatches, ~50-80us each, 102MB/layer s-plane HBM round-trip) is the
// next Amdahl term. Fuse: each block gathers its 64 rows' neighborhoods into a
// 16KB XOR-swizzled LDS tile (two 32-row batches), reads A-fragments from LDS,
// then runs the identical round-10 chunk loop with weight panels ALIASED over
// the same 16KB (barrier-separated). Deletes agg dispatches + s_hi/s_lo
// traffic; gathers overlap other blocks' MFMA at 4 blocks/CU (LDS 24.3KB).
// h ping-pongs between two workspace regions (no in-dispatch r/w race).
__global__ __launch_bounds__(256, 4) void gin_kernel(
    const ushort_t* __restrict__ hprev,   // [N,128] bf16 (previous layer)
    const int* __restrict__ row_off, const int* __restrict__ csr,
    const ushort_t* __restrict__ w1p, const float* __restrict__ b1s,
    const ushort_t* __restrict__ w2p, const float* __restrict__ b2s,
    float* __restrict__ hout_f32, ushort_t* __restrict__ hout_bf16) {
  __shared__ uint4 smemq[1024];      // 16KB: gather hi[8K]+lo[8K], later wA+wB
  __shared__ float zt[32 * 66];      // [k 0..31][m 0..63 +2 pad] = 8.25KB
  char* smem = (char*)smemq;
  ushort_t* wA = (ushort_t*)smemq;               // aliases gather-hi (8KB)
  ushort_t* wB = (ushort_t*)(smemq + 512);       // aliases gather-lo (8KB)
  const int tid = threadIdx.x;
  const int wave = tid >> 6;      // 0..3
  const int lane = tid & 63;
  const int quad = lane >> 4;
  const int l15 = lane & 15;
  const int m_base = wave * 16;   // 16 rows per wave
  const int row0 = blockIdx.x * 64;

  // ---- fused gather: two batches of 32 rows -> LDS tile -> A-fragments ----
  frag_b16 a_hi[4], a_lo[4];
  const uint4* hp = (const uint4*)hprev;  // 16 uint4 per 128-col row
  #pragma unroll 1
  for (int b = 0; b < 2; ++b) {
    #pragma unroll 1
    for (int half = 0; half < 2; ++half) {
      int rl = (tid >> 4) + half * 16;      // 0..31 (local row in batch)
      int lane16 = tid & 15;
      int gr = row0 + b * 32 + rl;
      int grc = (gr < NN) ? gr : NN - 1;    // clamp: stores guarded later
      float acc[8];
      {
        uint4 v = hp[(size_t)grc * 16 + lane16];
        bf2x(v.x, acc[0], acc[1]);
        bf2x(v.y, acc[2], acc[3]);
        bf2x(v.z, acc[4], acc[5]);
        bf2x(v.w, acc[6], acc[7]);
      }
      int e = row_off[grc];
      int e1 = row_off[grc + 1];
      for (; e + 1 < e1; e += 2) {  // two gathers in flight
        uint4 a = hp[(size_t)csr[e] * 16 + lane16];
        uint4 bq = hp[(size_t)csr[e + 1] * 16 + lane16];
        float f0, f1;
        bf2x(a.x, f0, f1); acc[0] += f0; acc[1] += f1;
        bf2x(a.y, f0, f1); acc[2] += f0; acc[3] += f1;
        bf2x(a.z, f0, f1); acc[4] += f0; acc[5] += f1;
        bf2x(a.w, f0, f1); acc[6] += f0; acc[7] += f1;
        bf2x(bq.x, f0, f1); acc[0] += f0; acc[1] += f1;
        bf2x(bq.y, f0, f1); acc[2] += f0; acc[3] += f1;
        bf2x(bq.z, f0, f1); acc[4] += f0; acc[5] += f1;
        bf2x(bq.w, f0, f1); acc[6] += f0; acc[7] += f1;
      }
      if (e < e1) {
        uint4 a = hp[(size_t)csr[e] * 16 + lane16];
        float f0, f1;
        bf2x(a.x, f0, f1); acc[0] += f0; acc[1] += f1;
        bf2x(a.y, f0, f1); acc[2] += f0; acc[3] += f1;
        bf2x(a.z, f0, f1); acc[4] += f0; acc[5] += f1;
        bf2x(a.w, f0, f1); acc[6] += f0; acc[7] += f1;
      }
      unsigned int hw[4], lw[4];
      #pragma unroll
      for (int i = 0; i < 4; ++i) {
        ushort_t h0, l0, h1, l1;
        split_bf16(acc[2 * i], h0, l0);
        split_bf16(acc[2 * i + 1], h1, l1);
        hw[i] = (unsigned int)h0 | ((unsigned int)h1 << 16);
        lw[i] = (unsigned int)l0 | ((unsigned int)l1 << 16);
      }
      // XOR-swizzled (G4) 16B slots: row-major [32][256B], bit4-6 ^= row&7
      int bo = (rl * 256 + lane16 * 16) ^ ((rl & 7) << 4);
      *(uint4*)(smem + bo) = make_uint4(hw[0], hw[1], hw[2], hw[3]);
      *(uint4*)(smem + 8192 + bo) = make_uint4(lw[0], lw[1], lw[2], lw[3]);
    }
    __syncthreads();  // gather tile ready
    if ((wave >> 1) == b) {  // waves owning this batch read their fragments
      int rl = (wave & 1) * 16 + l15;
      #pragma unroll
      for (int tk = 0; tk < 4; ++tk) {
        int bo = (rl * 256 + tk * 64 + quad * 16) ^ ((rl & 7) << 4);
        FragU uh, ul;
        uh.u = *(const uint4*)(smem + bo);
        ul.u = *(const uint4*)(smem + 8192 + bo);
        a_hi[tk] = uh.f;
        a_lo[tk] = ul.f;
      }
    }
    __syncthreads();  // frags read; tile reusable (batch 1 / weight panels)
  }

  frag_f32 hacc[8];
  #pragma unroll
  for (int tn = 0; tn < 8; ++tn) hacc[tn] = {0.f, 0.f, 0.f, 0.f};

  for (int ch = 0; ch < 16; ++ch) {
    // ---- stage both weight panels for this chunk (async DMA, then barrier) ----
    #pragma unroll
    for (int i = 0; i < 2; ++i)
      g2l16(w1p + ((size_t)(ch * 512 + i * 256 + tid)) * 8, wA + (i * 256 + tid) * 8);
    #pragma unroll
    for (int i = 0; i < 2; ++i)
      g2l16(w2p + ((size_t)(ch * 512 + i * 256 + tid)) * 8, wB + (i * 256 + tid) * 8);
    __syncthreads();  // drains vmcnt -> panels ready

    // ---- stage A: z[64 rows][32-col chunk] = relu(s @ W1[:, ch*32..+32] + b1) ----
    frag_f32 za[2];
    #pragma unroll
    for (int tn = 0; tn < 2; ++tn) za[tn] = {0.f, 0.f, 0.f, 0.f};

    #pragma unroll
    for (int tk = 0; tk < 4; ++tk) {
      #pragma unroll
      for (int tn = 0; tn < 2; ++tn) {
        FragU wv;
        wv.u = *(const uint4*)(wA + (tn * 4 + tk) * 512 + lane * 8);  // ds_read_b128
        za[tn] = __builtin_amdgcn_mfma_f32_16x16x32_bf16(a_hi[tk], wv.f, za[tn], 0, 0, 0);
        za[tn] = __builtin_amdgcn_mfma_f32_16x16x32_bf16(a_lo[tk], wv.f, za[tn], 0, 0, 0);
      }
    }

    // relu+bias, write wave-private zt slice (32 k-rows, this wave's 16 m)
    #pragma unroll
    for (int tn = 0; tn < 2; ++tn) {
      float b1v = b1s[ch * 32 + tn * 16 + l15];
      float z0 = fmaxf(za[tn][0] + b1v, 0.f);
      float z1 = fmaxf(za[tn][1] + b1v, 0.f);
      float z2 = fmaxf(za[tn][2] + b1v, 0.f);
      float z3 = fmaxf(za[tn][3] + b1v, 0.f);
      float* zp = &zt[(tn * 16 + l15) * 66 + m_base + quad * 4];
      *(float2*)zp = make_float2(z0, z1);
      *(float2*)(zp + 2) = make_float2(z2, z3);
    }
    // no barrier: each wave reads back only its own m-slice (lgkmcnt ordering)

    // ---- stage B: hacc += z @ W2[ch*32..+32, :] ----
    FragU zh, zl;
    #pragma unroll
    for (int j = 0; j < 8; ++j) {
      float v = zt[(quad * 8 + j) * 66 + m_base + l15];
      split_bf16(v, zh.s[j], zl.s[j]);
    }
    #pragma unroll
    for (int tn = 0; tn < 8; ++tn) {
      FragU wv;
      wv.u = *(const uint4*)(wB + tn * 512 + lane * 8);  // ds_read_b128
      hacc[tn] = __builtin_amdgcn_mfma_f32_16x16x32_bf16(zh.f, wv.f, hacc[tn], 0, 0, 0);
      hacc[tn] = __builtin_amdgcn_mfma_f32_16x16x32_bf16(zl.f, wv.f, hacc[tn], 0, 0, 0);
    }
    __syncthreads();  // all waves done reading wA/wB before next chunk overwrites
  }

  // ---- epilogue: h = relu(hacc + b2) -> fp32 and/or bf16 ----
  #pragma unroll
  for (int tn = 0; tn < 8; ++tn) {
    int col = tn * 16 + l15;
    float b2v = b2s[col];
    #pragma unroll
    for (int r = 0; r < 4; ++r) {
      int gr = row0 + m_base + quad * 4 + r;
      if (gr < NN) {
        float v = fmaxf(hacc[tn][r] + b2v, 0.f);
        if (hout_f32) hout_f32[(size_t)gr * DH + col] = v;
        if (hout_bf16) hout_bf16[(size_t)gr * DH + col] = rne_bf16(v);
      }
    }
  }
}

// ---------------- link predictor: MFMA (round-5 win) ----------------
__global__ __launch_bounds__(256, 2) void predict_kernel(
    const float* __restrict__ h, const int* __restrict__ psrc, const int* __restrict__ pdst,
    const int* __restrict__ nsrc, const int* __restrict__ ndst,
    const ushort_t* __restrict__ wp1p, const float* __restrict__ bp1,
    const float* __restrict__ Wp2, const float* __restrict__ bp2,
    float* __restrict__ out) {
  __shared__ unsigned int gp[128 * 128];  // [m][c] packed hi|lo bf16, 64 KB
  const int tid = threadIdx.x;
  const int wave = tid >> 6;
  const int lane = tid & 63;
  const int quad = lane >> 4;
  const int l15 = lane & 15;
  const int m_base = wave * 32;
  const int s0 = blockIdx.x * 128;

  // Wp1 B-fragments in registers (one-time, 16 recs x 16B per lane, coalesced)
  FragU wb1[4][4];
  #pragma unroll
  for (int tk = 0; tk < 4; ++tk)
    #pragma unroll
    for (int tn = 0; tn < 4; ++tn)
      wb1[tk][tn].u = *(const uint4*)(wp1p + ((size_t)((tk * 4 + tn) * 64 + lane)) * 8);

  // ---- phase 1: gather + product + split + pack (swizzled LDS write) ----
  #pragma unroll 8
  for (int i = 0; i < 16; ++i) {
    int idx = tid + i * 256;        // [0,4096)
    int m = idx >> 5;               // local sample
    int c4 = (idx & 31) << 2;       // starting col of this float4 chunk
    int smp = s0 + m;
    uint4 pk = make_uint4(0u, 0u, 0u, 0u);
    if (smp < 2 * PP) {
      int si = (smp < PP) ? psrc[smp] : nsrc[smp - PP];
      int di = (smp < PP) ? pdst[smp] : ndst[smp - PP];
      float4 a = *(const float4*)(h + (size_t)si * DH + c4);
      float4 b = *(const float4*)(h + (size_t)di * DH + c4);
      ushort_t hh, ll;
      split_bf16(a.x * b.x, hh, ll); pk.x = (unsigned)hh | ((unsigned)ll << 16);
      split_bf16(a.y * b.y, hh, ll); pk.y = (unsigned)hh | ((unsigned)ll << 16);
      split_bf16(a.z * b.z, hh, ll); pk.z = (unsigned)hh | ((unsigned)ll << 16);
      split_bf16(a.w * b.w, hh, ll); pk.w = (unsigned)hh | ((unsigned)ll << 16);
    }
    int slot = (m << 7) + c4;       // uint index, 16B-aligned chunk
    slot ^= (m & 7) << 2;           // XOR-swizzle (G4): spread rows over banks
    *(uint4*)(gp + slot) = pk;
  }
  __syncthreads();

  // ---- phase 2: z = g @ Wp1 via MFMA (hi + lo passes) ----
  frag_f32 za[2][4];
  #pragma unroll
  for (int ms = 0; ms < 2; ++ms)
    #pragma unroll
    for (int tn = 0; tn < 4; ++tn) za[ms][tn] = {0.f, 0.f, 0.f, 0.f};

  #pragma unroll
  for (int ms = 0; ms < 2; ++ms) {
    int m = m_base + ms * 16 + l15;
    int swz = (m & 7) << 2;
    #pragma unroll
    for (int tk = 0; tk < 4; ++tk) {
      int idx0 = (m << 7) + tk * 32 + quad * 8;
      uint4 u0 = *(const uint4*)(gp + (idx0 ^ swz));
      uint4 u1 = *(const uint4*)(gp + ((idx0 + 4) ^ swz));
      unsigned int uu[8];
      *(uint4*)uu = u0;
      *(uint4*)(uu + 4) = u1;
      FragU ah, al;
      #pragma unroll
      for (int j = 0; j < 8; ++j) {
        ah.s[j] = (ushort_t)(uu[j] & 0xFFFFu);
        al.s[j] = (ushort_t)(uu[j] >> 16);
      }
      #pragma unroll
      for (int tn = 0; tn < 4; ++tn) {
        za[ms][tn] = __builtin_amdgcn_mfma_f32_16x16x32_bf16(ah.f, wb1[tk][tn].f,
                                                             za[ms][tn], 0, 0, 0);
        za[ms][tn] = __builtin_amdgcn_mfma_f32_16x16x32_bf16(al.f, wb1[tk][tn].f,
                                                             za[ms][tn], 0, 0, 0);
      }
    }
  }

  // ---- epilogue: relu(z + bp1) . Wp2, 16-lane reduce, store ----
  float b1v[4], w2v[4];
  #pragma unroll
  for (int tn = 0; tn < 4; ++tn) {
    b1v[tn] = bp1[tn * 16 + l15];
    w2v[tn] = Wp2[tn * 16 + l15];
  }
  float bias = bp2[0];
  #pragma unroll
  for (int ms = 0; ms < 2; ++ms) {
    #pragma unroll
    for (int r = 0; r < 4; ++r) {
      float p = 0.f;
      #pragma unroll
      for (int tn = 0; tn < 4; ++tn)
        p += fmaxf(za[ms][tn][r] + b1v[tn], 0.f) * w2v[tn];
      p += __shfl_xor(p, 1, 64);
      p += __shfl_xor(p, 2, 64);
      p += __shfl_xor(p, 4, 64);
      p += __shfl_xor(p, 8, 64);
      if (l15 == 0) {
        int smp = s0 + m_base + ms * 16 + quad * 4 + r;
        if (smp < 2 * PP) out[smp] = p + bias;
      }
    }
  }
}

// ---------------- launcher ----------------
extern "C" void kernel_launch(void* const* d_in, const int* in_sizes, int n_in,
                              void* d_out, int out_size, void* d_ws, size_t ws_size,
                              hipStream_t stream) {
  const float* x   = (const float*)d_in[0];
  const float* W1  = (const float*)d_in[1];
  const float* b1  = (const float*)d_in[2];
  const float* W2  = (const float*)d_in[3];
  const float* b2  = (const float*)d_in[4];
  const float* Wp1 = (const float*)d_in[5];
  const float* bp1 = (const float*)d_in[6];
  const float* Wp2 = (const float*)d_in[7];
  const float* bp2 = (const float*)d_in[8];
  const int* esrc = (const int*)d_in[9];
  const int* edst = (const int*)d_in[10];
  const int* psrc = (const int*)d_in[11];
  const int* pdst = (const int*)d_in[12];
  const int* nsrc = (const int*)d_in[13];
  const int* ndst = (const int*)d_in[14];

  float* out = (float*)d_out;
  float* out_pred = out;               // [2P]
  float* hbuf = out + 2 * (size_t)PP;  // [N,128] fp32 final h (written by layer 2 only)

  // ---- workspace layout (~58.7 MB) — same offsets as before; s planes become
  //      the h ping-pong buffers (agg is fused, planes no longer needed) ----
  char* w = (char*)d_ws;
  ushort_t* hA   = (ushort_t*)w;                        // N*128 bf16 = 25.6 MB
  ushort_t* hB   = hA + (size_t)NN * DH;                // 25.6 MB
  ushort_t* w1p  = hB + (size_t)NN * DH;                // 3*128*64*8 ushorts = 393 KB
  ushort_t* w2p  = w1p + 3 * 128 * 64 * 8;              // 393 KB
  ushort_t* wp1p = w2p + 3 * 128 * 64 * 8;              // 16*64*8 ushorts = 16 KB
  int* row_off = (int*)(wp1p + 16 * 64 * 8);            // N+1
  int* csr     = row_off + (NN + 1);                    // E (6.4 MB)
  // CSR-build scratch aliases the (not-yet-written) hA region:
  int* deg    = (int*)w;
  int* inc    = deg + NN;
  int* bsum   = inc + NN;
  int* cursor = bsum + 256;

  // ---- CSR build ----
  hipMemsetAsync(deg, 0, NN * sizeof(int), stream);
  hist_kernel<<<(EE + 255) / 256, 256, 0, stream>>>(edst, deg);
  scan1_kernel<<<(NN + 511) / 512, 256, 0, stream>>>(deg, inc, bsum);
  scan2_kernel<<<1, 256, 0, stream>>>(bsum, (NN + 511) / 512);
  scan3_kernel<<<(NN + 255) / 256, 256, 0, stream>>>(inc, deg, bsum, row_off, cursor);
  scatter_kernel<<<SC_CHUNKS * SC_NW, 256, 0, stream>>>(esrc, edst, cursor, csr);

  // ---- pack weights (RNE bf16, MFMA fragment order, 16B records) ----
  pack_w1_kernel<<<96, 256, 0, stream>>>(W1, w1p);
  pack_w2_kernel<<<96, 256, 0, stream>>>(W2, w2p);
  pack_wp1_kernel<<<4, 256, 0, stream>>>(Wp1, wp1p);

  // ---- x -> bf16 into hA (after CSR scratch is dead; same stream) ----
  cvt_bf16_kernel<<<(NN * DH / 4 + 255) / 256, 256, 0, stream>>>(x, hA);

  // ---- 3 fused GIN layers: gather+MLP, h ping-pong hA <-> hB ----
  const int GB = (NN + 63) / 64;
  gin_kernel<<<GB, 256, 0, stream>>>(hA, row_off, csr,
      w1p + 0 * (size_t)128 * 64 * 8, b1 + 0 * (size_t)DM,
      w2p + 0 * (size_t)128 * 64 * 8, b2 + 0 * (size_t)DH, nullptr, hB);
  gin_kernel<<<GB, 256, 0, stream>>>(hB, row_off, csr,
      w1p + 1 * (size_t)128 * 64 * 8, b1 + 1 * (size_t)DM,
      w2p + 1 * (size_t)128 * 64 * 8, b2 + 1 * (size_t)DH, nullptr, hA);
  gin_kernel<<<GB, 256, 0, stream>>>(hA, row_off, csr,
      w1p + 2 * (size_t)128 * 64 * 8, b1 + 2 * (size_t)DM,
      w2p + 2 * (size_t)128 * 64 * 8, b2 + 2 * (size_t)DH, hbuf, nullptr);

  // ---- link prediction ----
  predict_kernel<<<(2 * PP + 127) / 128, 256, 0, stream>>>(
      hbuf, psrc, pdst, nsrc, ndst, wp1p, bp1, Wp2, bp2, out_pred);
}

// Round 12
// 728.199 us; speedup vs baseline: 1.0482x; 1.0482x over previous
//
#include <hip/hip_runtime.h>

typedef unsigned short ushort_t;

constexpr int NN = 100000;   // nodes
constexpr int EE = 1600000;  // edges
constexpr int PP = 100000;   // pos/neg samples
constexpr int DH = 128;
constexpr int DM = 512;

using frag_b16 = __attribute__((ext_vector_type(8))) short;   // 8 bf16 (4 VGPRs)
using frag_f32 = __attribute__((ext_vector_type(4))) float;   // 4 fp32 acc

union FragU {
  ushort_t s[8];
  uint4 u;
  frag_b16 f;
};

// split fp32 into bf16 hi (truncate) + bf16 lo (RNE of residual): x ~= hi+lo, err ~2^-17|x|
__device__ inline void split_bf16(float x, ushort_t& hi, ushort_t& lo) {
  unsigned int bx = __float_as_uint(x);
  hi = (ushort_t)(bx >> 16);
  float hf = __uint_as_float(bx & 0xFFFF0000u);
  float r = x - hf;
  unsigned int br = __float_as_uint(r);
  unsigned int rb = br + 0x7FFFu + ((br >> 16) & 1u);  // RNE
  lo = (ushort_t)(rb >> 16);
}

__device__ inline ushort_t rne_bf16(float x) {
  unsigned int u = __float_as_uint(x);
  unsigned int r = u + 0x7FFFu + ((u >> 16) & 1u);
  return (ushort_t)(r >> 16);
}

// unpack 2 bf16 from packed uint: low half -> a (even col), high half -> b (odd col)
__device__ inline void bf2x(unsigned int u, float& a, float& b) {
  a = __uint_as_float(u << 16);
  b = __uint_as_float(u & 0xFFFF0000u);
}

// async global->LDS 16B copy (dest: wave-uniform base + lane*16, src per-lane)
__device__ inline void g2l16(const ushort_t* __restrict__ g, ushort_t* l) {
  __builtin_amdgcn_global_load_lds(
      (const __attribute__((address_space(1))) void*)g,
      (__attribute__((address_space(3))) void*)l, 16, 0, 0);
}

// ---------------- CSR build (sort edges by dst, once per launch) ----------------

__global__ void hist_kernel(const int* __restrict__ dst, int* __restrict__ deg) {
  int i = blockIdx.x * 256 + threadIdx.x;
  if (i < EE) atomicAdd(&deg[dst[i]], 1);
}

__global__ void scan1_kernel(const int* __restrict__ deg, int* __restrict__ inc,
                             int* __restrict__ bsum) {
  __shared__ int buf[2][512];
  int base = blockIdx.x * 512;
  for (int i = threadIdx.x; i < 512; i += 256) {
    int g = base + i;
    buf[0][i] = (g < NN) ? deg[g] : 0;
  }
  __syncthreads();
  int cur = 0;
  for (int off = 1; off < 512; off <<= 1) {
    int nxt = cur ^ 1;
    for (int i = threadIdx.x; i < 512; i += 256) {
      int v = buf[cur][i];
      if (i >= off) v += buf[cur][i - off];
      buf[nxt][i] = v;
    }
    __syncthreads();
    cur = nxt;
  }
  for (int i = threadIdx.x; i < 512; i += 256) {
    int g = base + i;
    if (g < NN) inc[g] = buf[cur][i];
  }
  if (threadIdx.x == 0) bsum[blockIdx.x] = buf[cur][511];
}

__global__ void scan2_kernel(int* __restrict__ bsum, int nb) {
  __shared__ int buf[2][256];
  int i = threadIdx.x;
  buf[0][i] = (i < nb) ? bsum[i] : 0;
  __syncthreads();
  int cur = 0;
  for (int off = 1; off < 256; off <<= 1) {
    int nxt = cur ^ 1;
    int v = buf[cur][i];
    if (i >= off) v += buf[cur][i - off];
    buf[nxt][i] = v;
    __syncthreads();
    cur = nxt;
  }
  if (i < nb) bsum[i] = (i == 0) ? 0 : buf[cur][i - 1];
}

__global__ void scan3_kernel(const int* __restrict__ inc, const int* __restrict__ deg,
                             const int* __restrict__ bsum,
                             int* __restrict__ row_off, int* __restrict__ cursor) {
  int i = blockIdx.x * 256 + threadIdx.x;
  if (i < NN) {
    int excl = inc[i] - deg[i] + bsum[i >> 9];
    row_off[i] = excl;
    cursor[i] = excl;
    if (i == NN - 1) row_off[NN] = excl + deg[i];
  }
}

// Windowed, XCD-affine scatter (round 0 win). Window w handled only by blocks
// with blockIdx&7==w; each csr window written by one XCD -> clean writeback.
constexpr int SC_NW = 8;
constexpr int SC_WND = (NN + SC_NW - 1) / SC_NW;
constexpr int SC_EPB = 8192;
constexpr int SC_CHUNKS = (EE + SC_EPB - 1) / SC_EPB;

__global__ __launch_bounds__(256) void scatter_kernel(const int* __restrict__ esrc,
                                                      const int* __restrict__ edst,
                                                      int* __restrict__ cursor,
                                                      int* __restrict__ csr) {
  const int w = blockIdx.x & (SC_NW - 1);
  const int chunk = blockIdx.x / SC_NW;
  const int lo = w * SC_WND;
  const int hi = lo + SC_WND;
  const int base = chunk * SC_EPB;
  #pragma unroll 4
  for (int it = 0; it < SC_EPB / 256; ++it) {
    int i = base + it * 256 + threadIdx.x;
    if (i < EE) {
      int d = edst[i];
      if (d >= lo && d < hi) {
        int p = atomicAdd(&cursor[d], 1);
        csr[p] = esrc[i];
      }
    }
  }
}

// ---------------- weight packing: MFMA B-frag order, 16B records, RNE bf16 ----------
// record r = tile_global*64+lane holds 8 bf16 at wp + r*8 (ushorts).
// W1 [L][128(K)][512(N)]: tile = tn*4+tk (tn<32,tk<4), n=tn*16+(lane&15), k=tk*32+(lane>>4)*8+j
// -> per 32-col chunk ch, A-panel = tiles [ch*8, ch*8+8) CONTIGUOUS (8KB) for DMA.
__global__ void pack_w1_kernel(const float* __restrict__ W1, ushort_t* __restrict__ wp) {
  int t = blockIdx.x * 256 + threadIdx.x;
  if (t >= 3 * 128 * 64) return;
  int lane = t & 63;
  int tile = t >> 6;
  int tk = tile & 3;
  int tn = (tile >> 2) & 31;
  int layer = tile >> 7;
  int n = tn * 16 + (lane & 15);
  int k0 = tk * 32 + (lane >> 4) * 8;
  const float* src = W1 + (size_t)layer * DH * DM;
  size_t dst = (size_t)t * 8;
  #pragma unroll
  for (int j = 0; j < 8; ++j) wp[dst + j] = rne_bf16(src[(size_t)(k0 + j) * DM + n]);
}

// W2 [L][512(K)][128(N)]: ktg-major tile order: tile = ktg*8+tn (ktg<16, tn<8)
// -> per 32-k slab ch, B-panel = tiles [ch*8, ch*8+8) CONTIGUOUS (8KB) for DMA.
__global__ void pack_w2_kernel(const float* __restrict__ W2, ushort_t* __restrict__ wp) {
  int t = blockIdx.x * 256 + threadIdx.x;
  if (t >= 3 * 128 * 64) return;
  int lane = t & 63;
  int tile = t >> 6;
  int tn = tile & 7;
  int ktg = (tile >> 3) & 15;
  int layer = tile >> 7;
  int n = tn * 16 + (lane & 15);
  int k0 = ktg * 32 + (lane >> 4) * 8;
  const float* src = W2 + (size_t)layer * DM * DH;
  size_t dst = (size_t)t * 8;
  #pragma unroll
  for (int j = 0; j < 8; ++j) wp[dst + j] = rne_bf16(src[(size_t)(k0 + j) * DH + n]);
}

// Wp1 [128(K)][64(N)] -> MFMA B-frag records, tile = tk*4+tn (tk<4,tn<4)
__global__ void pack_wp1_kernel(const float* __restrict__ Wp1, ushort_t* __restrict__ wp) {
  int t = blockIdx.x * 256 + threadIdx.x;
  if (t >= 16 * 64) return;
  int lane = t & 63;
  int tile = t >> 6;
  int tn = tile & 3;
  int tk = tile >> 2;
  int n = tn * 16 + (lane & 15);
  int k0 = tk * 32 + (lane >> 4) * 8;
  size_t dst = (size_t)t * 8;
  #pragma unroll
  for (int j = 0; j < 8; ++j) wp[dst + j] = rne_bf16(Wp1[(size_t)(k0 + j) * 64 + n]);
}

// ---------------- x -> bf16 convert (layer-0 gather source) ----------------
__global__ void cvt_bf16_kernel(const float* __restrict__ x, ushort_t* __restrict__ xb) {
  int i = blockIdx.x * 256 + threadIdx.x;  // n = NN*DH/4 quads
  if (i < NN * DH / 4) {
    float4 v = ((const float4*)x)[i];
    ushort4 o;
    o.x = rne_bf16(v.x); o.y = rne_bf16(v.y); o.z = rne_bf16(v.z); o.w = rne_bf16(v.w);
    ((ushort4*)xb)[i] = o;
  }
}

// ---------------- aggregation: s[dst] = h[dst] + sum h[src] over bf16 h ----------------
// ROUND 12: 4 gathers in flight (was 2) — agg is the largest off-mlp Amdahl
// term; if latency-bound on L3 random-row reads, deeper pipeline halves stalls.
__global__ __launch_bounds__(256) void agg_kernel(const ushort_t* __restrict__ hbf,
                                                  const int* __restrict__ row_off,
                                                  const int* __restrict__ csr,
                                                  ushort_t* __restrict__ s_hi,
                                                  ushort_t* __restrict__ s_lo) {
  int t = blockIdx.x * 256 + threadIdx.x;
  int grp = t >> 4;
  int lane = t & 15;
  if (grp >= NN) return;
  const uint4* hp = (const uint4*)hbf;  // 16 uint4 per 128-col row
  float acc[8];
  {
    uint4 v = hp[(size_t)grp * 16 + lane];
    bf2x(v.x, acc[0], acc[1]);
    bf2x(v.y, acc[2], acc[3]);
    bf2x(v.z, acc[4], acc[5]);
    bf2x(v.w, acc[6], acc[7]);
  }
  int e = row_off[grp];
  int e1 = row_off[grp + 1];
  for (; e + 3 < e1; e += 4) {  // four gathers in flight
    uint4 a = hp[(size_t)csr[e] * 16 + lane];
    uint4 b = hp[(size_t)csr[e + 1] * 16 + lane];
    uint4 c = hp[(size_t)csr[e + 2] * 16 + lane];
    uint4 d = hp[(size_t)csr[e + 3] * 16 + lane];
    float f0, f1;
    bf2x(a.x, f0, f1); acc[0] += f0; acc[1] += f1;
    bf2x(a.y, f0, f1); acc[2] += f0; acc[3] += f1;
    bf2x(a.z, f0, f1); acc[4] += f0; acc[5] += f1;
    bf2x(a.w, f0, f1); acc[6] += f0; acc[7] += f1;
    bf2x(b.x, f0, f1); acc[0] += f0; acc[1] += f1;
    bf2x(b.y, f0, f1); acc[2] += f0; acc[3] += f1;
    bf2x(b.z, f0, f1); acc[4] += f0; acc[5] += f1;
    bf2x(b.w, f0, f1); acc[6] += f0; acc[7] += f1;
    bf2x(c.x, f0, f1); acc[0] += f0; acc[1] += f1;
    bf2x(c.y, f0, f1); acc[2] += f0; acc[3] += f1;
    bf2x(c.z, f0, f1); acc[4] += f0; acc[5] += f1;
    bf2x(c.w, f0, f1); acc[6] += f0; acc[7] += f1;
    bf2x(d.x, f0, f1); acc[0] += f0; acc[1] += f1;
    bf2x(d.y, f0, f1); acc[2] += f0; acc[3] += f1;
    bf2x(d.z, f0, f1); acc[4] += f0; acc[5] += f1;
    bf2x(d.w, f0, f1); acc[6] += f0; acc[7] += f1;
  }
  for (; e < e1; ++e) {
    uint4 a = hp[(size_t)csr[e] * 16 + lane];
    float f0, f1;
    bf2x(a.x, f0, f1); acc[0] += f0; acc[1] += f1;
    bf2x(a.y, f0, f1); acc[2] += f0; acc[3] += f1;
    bf2x(a.z, f0, f1); acc[4] += f0; acc[5] += f1;
    bf2x(a.w, f0, f1); acc[6] += f0; acc[7] += f1;
  }
  unsigned int hw[4], lw[4];
  #pragma unroll
  for (int i = 0; i < 4; ++i) {
    ushort_t h0, l0, h1, l1;
    split_bf16(acc[2 * i], h0, l0);
    split_bf16(acc[2 * i + 1], h1, l1);
    hw[i] = (unsigned int)h0 | ((unsigned int)h1 << 16);
    lw[i] = (unsigned int)l0 | ((unsigned int)l1 << 16);
  }
  size_t o = (size_t)grp * DH + lane * 8;
  *(uint4*)(s_hi + o) = make_uint4(hw[0], hw[1], hw[2], hw[3]);
  *(uint4*)(s_lo + o) = make_uint4(lw[0], lw[1], lw[2], lw[3]);
}

// ---------------- fused MFMA MLP, 16 rows/wave for 4 waves/SIMD (round-10 best) ----------
// Rounds 5/7/9 pinned mlp at ~88-90us across schedules; round-10's 16-rows/wave
// (VGPR 52, 4 blocks/CU) kept dur but doubled occupancy and won ~40us of
// inter-kernel overlap. Round-11 fusion with agg REGRESSED (gather lost its
// concurrent-block L2 locality: FETCH 27->188MB) — split design retained.
__global__ __launch_bounds__(256, 4) void mlp_kernel(
    const ushort_t* __restrict__ s_hi, const ushort_t* __restrict__ s_lo,
    const ushort_t* __restrict__ w1p, const float* __restrict__ b1s,
    const ushort_t* __restrict__ w2p, const float* __restrict__ b2s,
    float* __restrict__ hout_f32, ushort_t* __restrict__ hout_bf16) {
  __shared__ ushort_t wA[8 * 512];   // 8 tiles x 64 recs x 8 ushorts = 8KB
  __shared__ ushort_t wB[8 * 512];   // 8KB
  __shared__ float zt[32 * 66];      // [k 0..31][m 0..63 +2 pad] = 8.25KB
  const int tid = threadIdx.x;
  const int wave = tid >> 6;      // 0..3
  const int lane = tid & 63;
  const int quad = lane >> 4;
  const int l15 = lane & 15;
  const int m_base = wave * 16;   // 16 rows per wave
  const int row0 = blockIdx.x * 64;

  // ---- A-fragments: 1 m-tile x 4 k-tiles, bf16 hi/lo, in registers all kernel ----
  frag_b16 a_hi[4], a_lo[4];
  {
    int gr = row0 + m_base + l15;
    if (gr >= NN) gr = NN - 1;  // clamp: stores are guarded
    #pragma unroll
    for (int tk = 0; tk < 4; ++tk) {
      size_t o = (size_t)gr * DH + tk * 32 + quad * 8;
      FragU uh, ul;
      uh.u = *(const uint4*)(s_hi + o);
      ul.u = *(const uint4*)(s_lo + o);
      a_hi[tk] = uh.f;
      a_lo[tk] = ul.f;
    }
  }

  frag_f32 hacc[8];
  #pragma unroll
  for (int tn = 0; tn < 8; ++tn) hacc[tn] = {0.f, 0.f, 0.f, 0.f};

  for (int ch = 0; ch < 16; ++ch) {
    // ---- stage both weight panels for this chunk (async DMA, then barrier) ----
    #pragma unroll
    for (int i = 0; i < 2; ++i)
      g2l16(w1p + ((size_t)(ch * 512 + i * 256 + tid)) * 8, wA + (i * 256 + tid) * 8);
    #pragma unroll
    for (int i = 0; i < 2; ++i)
      g2l16(w2p + ((size_t)(ch * 512 + i * 256 + tid)) * 8, wB + (i * 256 + tid) * 8);
    __syncthreads();  // drains vmcnt -> panels ready

    // ---- stage A: z[64 rows][32-col chunk] = relu(s @ W1[:, ch*32..+32] + b1) ----
    frag_f32 za[2];
    #pragma unroll
    for (int tn = 0; tn < 2; ++tn) za[tn] = {0.f, 0.f, 0.f, 0.f};

    #pragma unroll
    for (int tk = 0; tk < 4; ++tk) {
      #pragma unroll
      for (int tn = 0; tn < 2; ++tn) {
        FragU wv;
        wv.u = *(const uint4*)(wA + (tn * 4 + tk) * 512 + lane * 8);  // ds_read_b128
        za[tn] = __builtin_amdgcn_mfma_f32_16x16x32_bf16(a_hi[tk], wv.f, za[tn], 0, 0, 0);
        za[tn] = __builtin_amdgcn_mfma_f32_16x16x32_bf16(a_lo[tk], wv.f, za[tn], 0, 0, 0);
      }
    }

    // relu+bias, write wave-private zt slice (32 k-rows, this wave's 16 m)
    #pragma unroll
    for (int tn = 0; tn < 2; ++tn) {
      float b1v = b1s[ch * 32 + tn * 16 + l15];
      float z0 = fmaxf(za[tn][0] + b1v, 0.f);
      float z1 = fmaxf(za[tn][1] + b1v, 0.f);
      float z2 = fmaxf(za[tn][2] + b1v, 0.f);
      float z3 = fmaxf(za[tn][3] + b1v, 0.f);
      float* zp = &zt[(tn * 16 + l15) * 66 + m_base + quad * 4];
      *(float2*)zp = make_float2(z0, z1);
      *(float2*)(zp + 2) = make_float2(z2, z3);
    }
    // no barrier: each wave reads back only its own m-slice (lgkmcnt ordering)

    // ---- stage B: hacc += z @ W2[ch*32..+32, :] ----
    FragU zh, zl;
    #pragma unroll
    for (int j = 0; j < 8; ++j) {
      float v = zt[(quad * 8 + j) * 66 + m_base + l15];
      split_bf16(v, zh.s[j], zl.s[j]);
    }
    #pragma unroll
    for (int tn = 0; tn < 8; ++tn) {
      FragU wv;
      wv.u = *(const uint4*)(wB + tn * 512 + lane * 8);  // ds_read_b128
      hacc[tn] = __builtin_amdgcn_mfma_f32_16x16x32_bf16(zh.f, wv.f, hacc[tn], 0, 0, 0);
      hacc[tn] = __builtin_amdgcn_mfma_f32_16x16x32_bf16(zl.f, wv.f, hacc[tn], 0, 0, 0);
    }
    __syncthreads();  // all waves done reading wA/wB before next chunk overwrites
  }

  // ---- epilogue: h = relu(hacc + b2) -> fp32 and/or bf16 ----
  #pragma unroll
  for (int tn = 0; tn < 8; ++tn) {
    int col = tn * 16 + l15;
    float b2v = b2s[col];
    #pragma unroll
    for (int r = 0; r < 4; ++r) {
      int gr = row0 + m_base + quad * 4 + r;
      if (gr < NN) {
        float v = fmaxf(hacc[tn][r] + b2v, 0.f);
        if (hout_f32) hout_f32[(size_t)gr * DH + col] = v;
        if (hout_bf16) hout_bf16[(size_t)gr * DH + col] = rne_bf16(v);
      }
    }
  }
}

// ---------------- link predictor: MFMA (round-5 win) ----------------
__global__ __launch_bounds__(256, 2) void predict_kernel(
    const float* __restrict__ h, const int* __restrict__ psrc, const int* __restrict__ pdst,
    const int* __restrict__ nsrc, const int* __restrict__ ndst,
    const ushort_t* __restrict__ wp1p, const float* __restrict__ bp1,
    const float* __restrict__ Wp2, const float* __restrict__ bp2,
    float* __restrict__ out) {
  __shared__ unsigned int gp[128 * 128];  // [m][c] packed hi|lo bf16, 64 KB
  const int tid = threadIdx.x;
  const int wave = tid >> 6;
  const int lane = tid & 63;
  const int quad = lane >> 4;
  const int l15 = lane & 15;
  const int m_base = wave * 32;
  const int s0 = blockIdx.x * 128;

  // Wp1 B-fragments in registers (one-time, 16 recs x 16B per lane, coalesced)
  FragU wb1[4][4];
  #pragma unroll
  for (int tk = 0; tk < 4; ++tk)
    #pragma unroll
    for (int tn = 0; tn < 4; ++tn)
      wb1[tk][tn].u = *(const uint4*)(wp1p + ((size_t)((tk * 4 + tn) * 64 + lane)) * 8);

  // ---- phase 1: gather + product + split + pack (swizzled LDS write) ----
  #pragma unroll 8
  for (int i = 0; i < 16; ++i) {
    int idx = tid + i * 256;        // [0,4096)
    int m = idx >> 5;               // local sample
    int c4 = (idx & 31) << 2;       // starting col of this float4 chunk
    int smp = s0 + m;
    uint4 pk = make_uint4(0u, 0u, 0u, 0u);
    if (smp < 2 * PP) {
      int si = (smp < PP) ? psrc[smp] : nsrc[smp - PP];
      int di = (smp < PP) ? pdst[smp] : ndst[smp - PP];
      float4 a = *(const float4*)(h + (size_t)si * DH + c4);
      float4 b = *(const float4*)(h + (size_t)di * DH + c4);
      ushort_t hh, ll;
      split_bf16(a.x * b.x, hh, ll); pk.x = (unsigned)hh | ((unsigned)ll << 16);
      split_bf16(a.y * b.y, hh, ll); pk.y = (unsigned)hh | ((unsigned)ll << 16);
      split_bf16(a.z * b.z, hh, ll); pk.z = (unsigned)hh | ((unsigned)ll << 16);
      split_bf16(a.w * b.w, hh, ll); pk.w = (unsigned)hh | ((unsigned)ll << 16);
    }
    int slot = (m << 7) + c4;       // uint index, 16B-aligned chunk
    slot ^= (m & 7) << 2;           // XOR-swizzle (G4): spread rows over banks
    *(uint4*)(gp + slot) = pk;
  }
  __syncthreads();

  // ---- phase 2: z = g @ Wp1 via MFMA (hi + lo passes) ----
  frag_f32 za[2][4];
  #pragma unroll
  for (int ms = 0; ms < 2; ++ms)
    #pragma unroll
    for (int tn = 0; tn < 4; ++tn) za[ms][tn] = {0.f, 0.f, 0.f, 0.f};

  #pragma unroll
  for (int ms = 0; ms < 2; ++ms) {
    int m = m_base + ms * 16 + l15;
    int swz = (m & 7) << 2;
    #pragma unroll
    for (int tk = 0; tk < 4; ++tk) {
      int idx0 = (m << 7) + tk * 32 + quad * 8;
      uint4 u0 = *(const uint4*)(gp + (idx0 ^ swz));
      uint4 u1 = *(const uint4*)(gp + ((idx0 + 4) ^ swz));
      unsigned int uu[8];
      *(uint4*)uu = u0;
      *(uint4*)(uu + 4) = u1;
      FragU ah, al;
      #pragma unroll
      for (int j = 0; j < 8; ++j) {
        ah.s[j] = (ushort_t)(uu[j] & 0xFFFFu);
        al.s[j] = (ushort_t)(uu[j] >> 16);
      }
      #pragma unroll
      for (int tn = 0; tn < 4; ++tn) {
        za[ms][tn] = __builtin_amdgcn_mfma_f32_16x16x32_bf16(ah.f, wb1[tk][tn].f,
                                                             za[ms][tn], 0, 0, 0);
        za[ms][tn] = __builtin_amdgcn_mfma_f32_16x16x32_bf16(al.f, wb1[tk][tn].f,
                                                             za[ms][tn], 0, 0, 0);
      }
    }
  }

  // ---- epilogue: relu(z + bp1) . Wp2, 16-lane reduce, store ----
  float b1v[4], w2v[4];
  #pragma unroll
  for (int tn = 0; tn < 4; ++tn) {
    b1v[tn] = bp1[tn * 16 + l15];
    w2v[tn] = Wp2[tn * 16 + l15];
  }
  float bias = bp2[0];
  #pragma unroll
  for (int ms = 0; ms < 2; ++ms) {
    #pragma unroll
    for (int r = 0; r < 4; ++r) {
      float p = 0.f;
      #pragma unroll
      for (int tn = 0; tn < 4; ++tn)
        p += fmaxf(za[ms][tn][r] + b1v[tn], 0.f) * w2v[tn];
      p += __shfl_xor(p, 1, 64);
      p += __shfl_xor(p, 2, 64);
      p += __shfl_xor(p, 4, 64);
      p += __shfl_xor(p, 8, 64);
      if (l15 == 0) {
        int smp = s0 + m_base + ms * 16 + quad * 4 + r;
        if (smp < 2 * PP) out[smp] = p + bias;
      }
    }
  }
}

// ---------------- launcher ----------------
extern "C" void kernel_launch(void* const* d_in, const int* in_sizes, int n_in,
                              void* d_out, int out_size, void* d_ws, size_t ws_size,
                              hipStream_t stream) {
  const float* x   = (const float*)d_in[0];
  const float* W1  = (const float*)d_in[1];
  const float* b1  = (const float*)d_in[2];
  const float* W2  = (const float*)d_in[3];
  const float* b2  = (const float*)d_in[4];
  const float* Wp1 = (const float*)d_in[5];
  const float* bp1 = (const float*)d_in[6];
  const float* Wp2 = (const float*)d_in[7];
  const float* bp2 = (const float*)d_in[8];
  const int* esrc = (const int*)d_in[9];
  const int* edst = (const int*)d_in[10];
  const int* psrc = (const int*)d_in[11];
  const int* pdst = (const int*)d_in[12];
  const int* nsrc = (const int*)d_in[13];
  const int* ndst = (const int*)d_in[14];

  float* out = (float*)d_out;
  float* out_pred = out;               // [2P]
  float* hbuf = out + 2 * (size_t)PP;  // [N,128] fp32 final h
  // intermediate bf16 h lives in the (dead until layer-2) hbuf region
  ushort_t* hbf = (ushort_t*)hbuf;     // [N,128] bf16 (25.6 MB of the 51.2 MB region)

  // ---- workspace layout (~58.7 MB) ----
  char* w = (char*)d_ws;
  ushort_t* s_hi = (ushort_t*)w;                        // N*128 bf16 = 25.6 MB
  ushort_t* s_lo = s_hi + (size_t)NN * DH;              // 25.6 MB
  ushort_t* w1p  = s_lo + (size_t)NN * DH;              // 3*128*64*8 ushorts = 393 KB
  ushort_t* w2p  = w1p + 3 * 128 * 64 * 8;              // 393 KB
  ushort_t* wp1p = w2p + 3 * 128 * 64 * 8;              // 16*64*8 ushorts = 16 KB
  int* row_off = (int*)(wp1p + 16 * 64 * 8);            // N+1
  int* csr     = row_off + (NN + 1);                    // E (6.4 MB)
  // CSR-build scratch aliases the (not-yet-written) s_hi region:
  int* deg    = (int*)w;
  int* inc    = deg + NN;
  int* bsum   = inc + NN;
  int* cursor = bsum + 256;

  // ---- CSR build ----
  hipMemsetAsync(deg, 0, NN * sizeof(int), stream);
  hist_kernel<<<(EE + 255) / 256, 256, 0, stream>>>(edst, deg);
  scan1_kernel<<<(NN + 511) / 512, 256, 0, stream>>>(deg, inc, bsum);
  scan2_kernel<<<1, 256, 0, stream>>>(bsum, (NN + 511) / 512);
  scan3_kernel<<<(NN + 255) / 256, 256, 0, stream>>>(inc, deg, bsum, row_off, cursor);
  scatter_kernel<<<SC_CHUNKS * SC_NW, 256, 0, stream>>>(esrc, edst, cursor, csr);

  // ---- pack weights (RNE bf16, MFMA fragment order, 16B records) ----
  pack_w1_kernel<<<96, 256, 0, stream>>>(W1, w1p);
  pack_w2_kernel<<<96, 256, 0, stream>>>(W2, w2p);
  pack_wp1_kernel<<<4, 256, 0, stream>>>(Wp1, wp1p);

  // ---- x -> bf16 for layer-0 gather ----
  cvt_bf16_kernel<<<(NN * DH / 4 + 255) / 256, 256, 0, stream>>>(x, hbf);

  // ---- 3 GIN layers: agg(hbf -> s planes), mlp(s -> hbf or hbuf) ----
  for (int l = 0; l < 3; ++l) {
    agg_kernel<<<(NN * 16 + 255) / 256, 256, 0, stream>>>(hbf, row_off, csr, s_hi, s_lo);
    mlp_kernel<<<(NN + 63) / 64, 256, 0, stream>>>(
        s_hi, s_lo,
        w1p + (size_t)l * 128 * 64 * 8, b1 + (size_t)l * DM,
        w2p + (size_t)l * 128 * 64 * 8, b2 + (size_t)l * DH,
        (l == 2) ? hbuf : nullptr, (l == 2) ? nullptr : hbf);
  }

  // ---- link prediction ----
  predict_kernel<<<(2 * PP + 127) / 128, 256, 0, stream>>>(
      hbuf, psrc, pdst, nsrc, ndst, wp1p, bp1, Wp2, bp2, out_pred);
}